// Round 1
// baseline (27076.520 us; speedup 1.0000x reference)
//
#include <hip/hip_runtime.h>
#include <math.h>

#define Bq 4
#define Mq 500
#define Nq 500
#define Cq 91

// ---------------------------------------------------------------------------
// Phase 1: cost[b,i,j] = 0.5*||center2_i - center1_j||_2
//                      + 0.5*max_c |sigmoid(l2[i,c]) - sigmoid(l1[j,c])|
// 16x16 (i,j) tile per 256-thread block; sigmoid applied during LDS staging.
// ---------------------------------------------------------------------------
__device__ __forceinline__ float sigmoidf_(float x) {
    return 1.0f / (1.0f + expf(-x));
}

__global__ __launch_bounds__(256) void cost_kernel(
    const float* __restrict__ p1_boxes, const float* __restrict__ p1_logits,
    const float* __restrict__ p2_boxes, const float* __restrict__ p2_logits,
    float* __restrict__ cost)
{
    __shared__ float s2t[16][Cq + 1];   // +1 pad: stride 92 -> only 2-way bank alias (free)
    __shared__ float s1t[16][Cq + 1];
    __shared__ float b2x[16], b2y[16], b1x[16], b1y[16];
    const int b  = blockIdx.z;
    const int i0 = blockIdx.y * 16;
    const int j0 = blockIdx.x * 16;
    const int tid = threadIdx.x;

    for (int t = tid; t < 16 * Cq; t += 256) {
        const int r = t / Cq, c = t - r * Cq;
        const int i = min(i0 + r, Mq - 1);   // clamp: guarded compute threads never write
        const int j = min(j0 + r, Nq - 1);
        s2t[r][c] = sigmoidf_(p2_logits[((size_t)b * Mq + i) * Cq + c]);
        s1t[r][c] = sigmoidf_(p1_logits[((size_t)b * Nq + j) * Cq + c]);
    }
    if (tid < 16) {
        const int i = min(i0 + tid, Mq - 1);
        const int j = min(j0 + tid, Nq - 1);
        b2x[tid] = p2_boxes[((size_t)b * Mq + i) * 4 + 0];
        b2y[tid] = p2_boxes[((size_t)b * Mq + i) * 4 + 1];
        b1x[tid] = p1_boxes[((size_t)b * Nq + j) * 4 + 0];
        b1y[tid] = p1_boxes[((size_t)b * Nq + j) * 4 + 1];
    }
    __syncthreads();

    const int ty = tid >> 4, tx = tid & 15;
    const int i = i0 + ty, j = j0 + tx;
    if (i < Mq && j < Nq) {
        float mx = 0.0f;
        #pragma unroll 7
        for (int c = 0; c < Cq; ++c)
            mx = fmaxf(mx, fabsf(s2t[ty][c] - s1t[tx][c]));
        const float dx = b2x[ty] - b1x[tx];
        const float dy = b2y[ty] - b1y[tx];
        const float cd = sqrtf(dx * dx + dy * dy);
        cost[((size_t)b * Mq + i) * Nq + j] = 0.5f * cd + 0.5f * mx;
    }
}

// ---------------------------------------------------------------------------
// Phase 2: exact LAPJV shortest-augmenting-path (faithful port of the numpy
// reference, float64 duals). One block = one batch, ONE wave of 64 lanes.
// Lane L owns columns {L, L+64, ..., L+448} -> shortest/path/remaining/v for
// those columns are only ever touched by their owner inside the hot loop, so
// the Dijkstra while-loop needs NO barriers; cross-lane state (u, row4col,
// col4row, SR_flag) is only mutated at end-of-row behind __syncthreads().
// Argmin reduction = 6-step shfl_xor butterfly with np.argmin's
// lowest-index tie-break.
// ---------------------------------------------------------------------------
__global__ __launch_bounds__(64) void lsa_kernel(
    const float* __restrict__ cost, int* __restrict__ mapping)
{
    constexpr int n = Nq;  // square: 500
    __shared__ double u_s[512], v_s[512], shortest_s[512];
    __shared__ int path_s[512], row4col_s[512], col4row_s[512];
    __shared__ unsigned char remaining_s[512], SR_flag[512];

    const int lane = threadIdx.x;
    const int b = blockIdx.x;
    const float* __restrict__ cb = cost + (size_t)b * n * n;

    for (int t = lane; t < n; t += 64) {
        u_s[t] = 0.0; v_s[t] = 0.0;
        row4col_s[t] = -1; col4row_s[t] = -1;
    }
    __syncthreads();

    for (int cur_row = 0; cur_row < n; ++cur_row) {
        for (int t = lane; t < n; t += 64) {
            remaining_s[t] = 1;
            shortest_s[t] = (double)INFINITY;
            path_s[t] = -1;
            SR_flag[t] = 0;
        }
        __syncthreads();

        int sink = -1;
        int i = cur_row;
        double min_val = 0.0;

        for (int guard = 0; guard < n && sink < 0; ++guard) {
            if (lane == 0) SR_flag[i] = 1;
            const double ui = u_s[i];
            const float* __restrict__ crow = cb + (size_t)i * n;

            // Issue all 8 cost loads up-front (independent, coalesced).
            float cvals[8];
            #pragma unroll
            for (int k = 0; k < 8; ++k) {
                const int j = lane + (k << 6);
                cvals[k] = (j < n) ? crow[j] : 0.0f;
            }

            double lmin = (double)INFINITY;
            int lidx = 0x7fffffff;
            #pragma unroll
            for (int k = 0; k < 8; ++k) {
                const int j = lane + (k << 6);
                if (j < n && remaining_s[j]) {
                    const double r = min_val + (double)cvals[k] - ui - v_s[j];
                    double s = shortest_s[j];
                    if (r < s) { shortest_s[j] = r; path_s[j] = i; s = r; }
                    // k ascending => j ascending within lane: '<' keeps first min
                    if (s < lmin) { lmin = s; lidx = j; }
                }
            }
            // butterfly argmin over 64 lanes; ties -> lowest column index
            for (int off = 32; off > 0; off >>= 1) {
                const double om = __shfl_xor(lmin, off);
                const int    oi = __shfl_xor(lidx, off);
                if (om < lmin || (om == lmin && oi < lidx)) { lmin = om; lidx = oi; }
            }
            min_val = lmin;
            const int jst = lidx;
            if ((jst & 63) == lane) remaining_s[jst] = 0;  // owner writes, owner reads
            const int r4c = row4col_s[jst];                 // stable during this row
            if (r4c < 0) sink = jst; else i = r4c;
        }
        __syncthreads();  // publish shortest/path/SR_flag for cross-lane reads

        // dual updates: u[sr] += min_val - shortest[col4row[sr]] (sr = SR\{cur_row});
        //               v[~remaining] -= min_val - shortest[~remaining]
        for (int t = lane; t < n; t += 64) {
            if (SR_flag[t] && t != cur_row) {
                const int c = col4row_s[t];
                u_s[t] += min_val - shortest_s[c];
            }
            if (!remaining_s[t]) {
                v_s[t] -= min_val - shortest_s[t];
            }
        }
        __syncthreads();

        if (lane == 0) {
            u_s[cur_row] += min_val;
            // augment along alternating path
            int j = sink;
            while (true) {
                const int ii = path_s[j];
                row4col_s[j] = ii;
                const int tmp = col4row_s[ii];
                col4row_s[ii] = j;
                j = tmp;
                if (ii == cur_row) break;
            }
        }
        __syncthreads();
    }

    for (int t = lane; t < n; t += 64)
        mapping[b * n + t] = col4row_s[t];
}

// ---------------------------------------------------------------------------
// Phase 3: extrapolation. Square problem => every row assigned (has == true).
// ---------------------------------------------------------------------------
__global__ __launch_bounds__(256) void extrap_boxes_kernel(
    const float* __restrict__ p1_boxes, const float* __restrict__ p2_boxes,
    const float* __restrict__ toffs, const int* __restrict__ mapping,
    float* __restrict__ out_boxes)
{
    const int idx = blockIdx.x * blockDim.x + threadIdx.x;  // b*Mq + i
    if (idx >= Bq * Mq) return;
    const int b = idx / Mq;
    const float t0 = toffs[b * 3 + 0], t1 = toffs[b * 3 + 1], t2 = toffs[b * 3 + 2];
    const float factor = (t2 - t1) / (t1 - t0);
    const int m = mapping[idx];
    const float4 p2 = ((const float4*)p2_boxes)[idx];
    const float4 p1 = ((const float4*)p1_boxes)[b * Nq + m];
    float4 o;
    o.x = p2.x + (p2.x - p1.x) * factor;
    o.y = p2.y + (p2.y - p1.y) * factor;
    o.z = fmaxf(p2.z + (p2.z - p1.z) * factor, 0.0f);
    o.w = fmaxf(p2.w + (p2.w - p1.w) * factor, 0.0f);
    ((float4*)out_boxes)[idx] = o;
}

__global__ __launch_bounds__(256) void extrap_logits_kernel(
    const float* __restrict__ p1_logits, const float* __restrict__ p2_logits,
    const int* __restrict__ mapping, float* __restrict__ out_logits)
{
    const int idx = blockIdx.x * blockDim.x + threadIdx.x;  // (b*Mq + i)*Cq + c
    if (idx >= Bq * Mq * Cq) return;
    const int c = idx % Cq;
    const int bi = idx / Cq;
    const int b = bi / Mq;
    const int m = mapping[bi];
    out_logits[idx] = 0.5f * (p2_logits[idx] + p1_logits[((size_t)b * Nq + m) * Cq + c]);
}

// ---------------------------------------------------------------------------
extern "C" void kernel_launch(void* const* d_in, const int* in_sizes, int n_in,
                              void* d_out, int out_size, void* d_ws, size_t ws_size,
                              hipStream_t stream) {
    const float* p1_boxes  = (const float*)d_in[0];  // (B,N,4)
    const float* p1_logits = (const float*)d_in[1];  // (B,N,C)
    const float* p2_boxes  = (const float*)d_in[2];  // (B,M,4)
    const float* p2_logits = (const float*)d_in[3];  // (B,M,C)
    const float* toffs     = (const float*)d_in[4];  // (B,3)
    float* out = (float*)d_out;                      // boxes3 (B*M*4) ++ logits3 (B*M*C)

    float* cost   = (float*)d_ws;                                          // 4*500*500 f32 = 4 MB
    int*   mapping = (int*)((char*)d_ws + (size_t)Bq * Mq * Nq * sizeof(float));  // 4*500 i32

    dim3 cgrid((Nq + 15) / 16, (Mq + 15) / 16, Bq);
    cost_kernel<<<cgrid, 256, 0, stream>>>(p1_boxes, p1_logits, p2_boxes, p2_logits, cost);

    lsa_kernel<<<Bq, 64, 0, stream>>>(cost, mapping);

    extrap_boxes_kernel<<<(Bq * Mq + 255) / 256, 256, 0, stream>>>(
        p1_boxes, p2_boxes, toffs, mapping, out);
    extrap_logits_kernel<<<(Bq * Mq * Cq + 255) / 256, 256, 0, stream>>>(
        p1_logits, p2_logits, mapping, out + Bq * Mq * 4);
}

// Round 2
// 7999.483 us; speedup vs baseline: 3.3848x; 3.3848x over previous
//
#include <hip/hip_runtime.h>
#include <math.h>

#define Bq 4
#define Mq 500
#define Nq 500
#define Cq 91

// ---------------------------------------------------------------------------
// Phase 1: cost[b,i,j] = 0.5*||center2_i - center1_j||_2
//                      + 0.5*max_c |sigmoid(l2[i,c]) - sigmoid(l1[j,c])|
// ---------------------------------------------------------------------------
__device__ __forceinline__ float sigmoidf_(float x) {
    return 1.0f / (1.0f + expf(-x));
}

__global__ __launch_bounds__(256) void cost_kernel(
    const float* __restrict__ p1_boxes, const float* __restrict__ p1_logits,
    const float* __restrict__ p2_boxes, const float* __restrict__ p2_logits,
    float* __restrict__ cost)
{
    __shared__ float s2t[16][Cq + 1];   // stride 92 -> 2-way bank alias (free)
    __shared__ float s1t[16][Cq + 1];
    __shared__ float b2x[16], b2y[16], b1x[16], b1y[16];
    const int b  = blockIdx.z;
    const int i0 = blockIdx.y * 16;
    const int j0 = blockIdx.x * 16;
    const int tid = threadIdx.x;

    for (int t = tid; t < 16 * Cq; t += 256) {
        const int r = t / Cq, c = t - r * Cq;
        const int i = min(i0 + r, Mq - 1);
        const int j = min(j0 + r, Nq - 1);
        s2t[r][c] = sigmoidf_(p2_logits[((size_t)b * Mq + i) * Cq + c]);
        s1t[r][c] = sigmoidf_(p1_logits[((size_t)b * Nq + j) * Cq + c]);
    }
    if (tid < 16) {
        const int i = min(i0 + tid, Mq - 1);
        const int j = min(j0 + tid, Nq - 1);
        b2x[tid] = p2_boxes[((size_t)b * Mq + i) * 4 + 0];
        b2y[tid] = p2_boxes[((size_t)b * Mq + i) * 4 + 1];
        b1x[tid] = p1_boxes[((size_t)b * Nq + j) * 4 + 0];
        b1y[tid] = p1_boxes[((size_t)b * Nq + j) * 4 + 1];
    }
    __syncthreads();

    const int ty = tid >> 4, tx = tid & 15;
    const int i = i0 + ty, j = j0 + tx;
    if (i < Mq && j < Nq) {
        float mx = 0.0f;
        #pragma unroll 7
        for (int c = 0; c < Cq; ++c)
            mx = fmaxf(mx, fabsf(s2t[ty][c] - s1t[tx][c]));
        const float dx = b2x[ty] - b1x[tx];
        const float dy = b2y[ty] - b1y[tx];
        const float cd = sqrtf(dx * dx + dy * dy);
        cost[((size_t)b * Mq + i) * Nq + j] = 0.5f * cd + 0.5f * mx;
    }
}

// ---------------------------------------------------------------------------
// Phase 1.5: column reduction. v0[b][j] = min_i cost[b][i][j], amin = argmin.
// Lanes j consecutive -> every row read is coalesced.
// ---------------------------------------------------------------------------
__global__ __launch_bounds__(256) void colred_kernel(
    const float* __restrict__ cost, float* __restrict__ v0, int* __restrict__ amin)
{
    const int j = blockIdx.x * 256 + threadIdx.x;
    const int b = blockIdx.y;
    if (j >= Nq) return;
    const float* __restrict__ cb = cost + (size_t)b * Mq * Nq;
    float best = INFINITY;
    int bi = 0;
    #pragma unroll 4
    for (int i = 0; i < Mq; ++i) {
        const float c = cb[(size_t)i * Nq + j];
        if (c < best) { best = c; bi = i; }
    }
    v0[b * Nq + j] = best;
    amin[b * Nq + j] = bi;
}

// ---------------------------------------------------------------------------
// Phase 2: exact successive-shortest-path LAP (same optimum as reference's
// LAPJV port). One block = one batch, ONE wave. Lane L owns columns
// {L, L+64, ...}: v/shortest/path/remaining live in REGISTERS, so the
// Dijkstra hot loop touches LDS only once per pop (fused (row4col, u) pair,
// ds_read_b64) plus the L2-resident cost-row load. Argmin = u64-packed
// (f32bits<<32 | col) 6-step shfl_xor butterfly; reduced costs >= 0 (clamped)
// so float-bit order == uint order, and packed min gives np.argmin's
// lowest-index tie-break.
// Init: column reduction duals + greedy tight-edge matching (exact JV-style
// preprocessing -> identical unique optimal assignment, far fewer pops).
// ---------------------------------------------------------------------------
__global__ __launch_bounds__(64) void lsa_kernel(
    const float* __restrict__ cost, const float* __restrict__ v0,
    const int* __restrict__ amin, int* __restrict__ mapping)
{
    constexpr int n = Nq;  // 500
    __shared__ int2  pair_lds[512];      // {row4col[j], f32bits(u[row4col[j]])}
    __shared__ float u_lds[512];
    __shared__ float shortest_lds[512];
    __shared__ int   path_lds[512];
    __shared__ int   row4col_lds[512];
    __shared__ int   col4row_lds[512];

    const int lane = threadIdx.x;
    const int b = blockIdx.x;
    const float* __restrict__ cb = cost + (size_t)b * n * n;

    const unsigned init_mask = (lane < (n & 63)) ? 0xFFu : 0x7Fu;  // k=7 valid iff lane<52

    float v_r[8], short_r[8];
    int path_r[8];

    // --- init: duals, greedy matching on tight edges ---
    #pragma unroll
    for (int k = 0; k < 8; ++k) {
        const int j = lane + (k << 6);
        v_r[k] = (j < n) ? v0[b * n + j] : 0.0f;
        short_r[k] = INFINITY;
        path_r[k] = -1;
        if (j < n) path_lds[j] = amin[b * n + j];   // stash argmins for lane0
    }
    for (int t = lane; t < 512; t += 64) {
        u_lds[t] = 0.0f; row4col_lds[t] = -1; col4row_lds[t] = -1;
    }
    __syncthreads();
    if (lane == 0) {
        for (int j = 0; j < n; ++j) {
            const int i0 = path_lds[j];
            if (col4row_lds[i0] < 0) { col4row_lds[i0] = j; row4col_lds[j] = i0; }
        }
    }
    __syncthreads();
    #pragma unroll
    for (int k = 0; k < 8; ++k) {
        const int j = lane + (k << 6);
        if (j < n) {
            const int rr = row4col_lds[j];
            pair_lds[j] = make_int2(rr, rr >= 0 ? __float_as_int(u_lds[rr]) : 0);
            path_lds[j] = -1;
        }
    }
    unsigned rem = init_mask;
    unsigned sr_mask = 0;
    __syncthreads();

    // --- successive shortest paths over unassigned rows ---
    for (int cur_row = 0; cur_row < n; ++cur_row) {
        if (col4row_lds[cur_row] >= 0) continue;   // wave-uniform

        int sink = -1;
        int i = cur_row;
        float min_val = 0.0f;
        float a = -u_lds[cur_row];                  // a = min_val - u[i]
        const float* __restrict__ crow = cb + (size_t)i * n;

        for (;;) {
            if (((i ^ lane) & 63) == 0) sr_mask |= 1u << (i >> 6);

            float cv[8];
            #pragma unroll
            for (int k = 0; k < 8; ++k) {
                const int j = lane + (k << 6);
                cv[k] = crow[j < n ? j : 0];
            }

            unsigned long long best = ~0ull;
            #pragma unroll
            for (int k = 0; k < 8; ++k) {
                if (rem & (1u << k)) {
                    const int j = lane + (k << 6);
                    const float r = fmaxf(a + cv[k] - v_r[k], 0.0f);
                    if (r < short_r[k]) { short_r[k] = r; path_r[k] = i; }
                    const unsigned long long key =
                        ((unsigned long long)__float_as_uint(short_r[k]) << 32) | (unsigned)j;
                    if (key < best) best = key;
                }
            }
            #pragma unroll
            for (int off = 32; off; off >>= 1) {
                const unsigned long long o = __shfl_xor(best, off);
                if (o < best) best = o;
            }
            min_val = __uint_as_float((unsigned)(best >> 32));
            const int jst = (int)(best & 0xFFFFFFFFu);
            if (((jst ^ lane) & 63) == 0) rem &= ~(1u << (jst >> 6));

            const int2 pr = pair_lds[jst];          // {row4col[jst], bits(u)}
            if (pr.x < 0) { sink = jst; break; }
            i = pr.x;
            a = min_val - __int_as_float(pr.y);
            crow = cb + (size_t)i * n;
        }

        // --- end of row: publish shortest/path ---
        #pragma unroll
        for (int k = 0; k < 8; ++k) {
            const int j = lane + (k << 6);
            if (j < n) { shortest_lds[j] = short_r[k]; path_lds[j] = path_r[k]; }
        }
        __syncthreads();

        // dual updates (col4row read BEFORE augmentation, per reference)
        #pragma unroll
        for (int k = 0; k < 8; ++k) {
            const int t = lane + (k << 6);
            if (t < n && (sr_mask & (1u << k))) {
                if (t == cur_row) u_lds[t] += min_val;
                else              u_lds[t] += min_val - shortest_lds[col4row_lds[t]];
            }
        }
        const unsigned scanned = init_mask & ~rem;
        #pragma unroll
        for (int k = 0; k < 8; ++k)
            if (scanned & (1u << k)) v_r[k] -= min_val - short_r[k];
        __syncthreads();

        if (lane == 0) {   // augment alternating path
            int j = sink;
            for (;;) {
                const int ii = path_lds[j];
                row4col_lds[j] = ii;
                const int tmp = col4row_lds[ii];
                col4row_lds[ii] = j;
                j = tmp;
                if (ii == cur_row) break;
            }
        }
        __syncthreads();

        // rebuild (row4col, u) pairs; reset per-row register state
        #pragma unroll
        for (int k = 0; k < 8; ++k) {
            const int j = lane + (k << 6);
            if (j < n) {
                const int rr = row4col_lds[j];
                pair_lds[j] = make_int2(rr, rr >= 0 ? __float_as_int(u_lds[rr]) : 0);
            }
            short_r[k] = INFINITY;
            path_r[k] = -1;
        }
        rem = init_mask;
        sr_mask = 0;
        __syncthreads();
    }

    for (int t = lane; t < n; t += 64)
        mapping[b * n + t] = col4row_lds[t];
}

// ---------------------------------------------------------------------------
// Phase 3: extrapolation (square problem => every row assigned).
// ---------------------------------------------------------------------------
__global__ __launch_bounds__(256) void extrap_boxes_kernel(
    const float* __restrict__ p1_boxes, const float* __restrict__ p2_boxes,
    const float* __restrict__ toffs, const int* __restrict__ mapping,
    float* __restrict__ out_boxes)
{
    const int idx = blockIdx.x * blockDim.x + threadIdx.x;  // b*Mq + i
    if (idx >= Bq * Mq) return;
    const int b = idx / Mq;
    const float t0 = toffs[b * 3 + 0], t1 = toffs[b * 3 + 1], t2 = toffs[b * 3 + 2];
    const float factor = (t2 - t1) / (t1 - t0);
    const int m = mapping[idx];
    const float4 p2 = ((const float4*)p2_boxes)[idx];
    const float4 p1 = ((const float4*)p1_boxes)[b * Nq + m];
    float4 o;
    o.x = p2.x + (p2.x - p1.x) * factor;
    o.y = p2.y + (p2.y - p1.y) * factor;
    o.z = fmaxf(p2.z + (p2.z - p1.z) * factor, 0.0f);
    o.w = fmaxf(p2.w + (p2.w - p1.w) * factor, 0.0f);
    ((float4*)out_boxes)[idx] = o;
}

__global__ __launch_bounds__(256) void extrap_logits_kernel(
    const float* __restrict__ p1_logits, const float* __restrict__ p2_logits,
    const int* __restrict__ mapping, float* __restrict__ out_logits)
{
    const int idx = blockIdx.x * blockDim.x + threadIdx.x;  // (b*Mq + i)*Cq + c
    if (idx >= Bq * Mq * Cq) return;
    const int c = idx % Cq;
    const int bi = idx / Cq;
    const int b = bi / Mq;
    const int m = mapping[bi];
    out_logits[idx] = 0.5f * (p2_logits[idx] + p1_logits[((size_t)b * Nq + m) * Cq + c]);
}

// ---------------------------------------------------------------------------
extern "C" void kernel_launch(void* const* d_in, const int* in_sizes, int n_in,
                              void* d_out, int out_size, void* d_ws, size_t ws_size,
                              hipStream_t stream) {
    const float* p1_boxes  = (const float*)d_in[0];  // (B,N,4)
    const float* p1_logits = (const float*)d_in[1];  // (B,N,C)
    const float* p2_boxes  = (const float*)d_in[2];  // (B,M,4)
    const float* p2_logits = (const float*)d_in[3];  // (B,M,C)
    const float* toffs     = (const float*)d_in[4];  // (B,3)
    float* out = (float*)d_out;                      // boxes3 ++ logits3

    char* ws = (char*)d_ws;
    float* cost    = (float*)ws;                                   // 4 MB
    int*   mapping = (int*)  (ws + 4000000);                       // 8 KB
    float* v0      = (float*)(ws + 4008000);                       // 8 KB
    int*   amin    = (int*)  (ws + 4016000);                       // 8 KB

    dim3 cgrid((Nq + 15) / 16, (Mq + 15) / 16, Bq);
    cost_kernel<<<cgrid, 256, 0, stream>>>(p1_boxes, p1_logits, p2_boxes, p2_logits, cost);

    colred_kernel<<<dim3(2, Bq), 256, 0, stream>>>(cost, v0, amin);

    lsa_kernel<<<Bq, 64, 0, stream>>>(cost, v0, amin, mapping);

    extrap_boxes_kernel<<<(Bq * Mq + 255) / 256, 256, 0, stream>>>(
        p1_boxes, p2_boxes, toffs, mapping, out);
    extrap_logits_kernel<<<(Bq * Mq * Cq + 255) / 256, 256, 0, stream>>>(
        p1_logits, p2_logits, mapping, out + Bq * Mq * 4);
}

// Round 3
// 6531.017 us; speedup vs baseline: 4.1458x; 1.2248x over previous
//
#include <hip/hip_runtime.h>
#include <math.h>

#define Bq 4
#define Mq 500
#define Nq 500
#define Cq 91

// ---------------------------------------------------------------------------
// Phase 1: cost[b,i,j] = 0.5*||center2_i - center1_j||_2
//                      + 0.5*max_c |sigmoid(l2[i,c]) - sigmoid(l1[j,c])|
// ---------------------------------------------------------------------------
__device__ __forceinline__ float sigmoidf_(float x) {
    return 1.0f / (1.0f + expf(-x));
}

__global__ __launch_bounds__(256) void cost_kernel(
    const float* __restrict__ p1_boxes, const float* __restrict__ p1_logits,
    const float* __restrict__ p2_boxes, const float* __restrict__ p2_logits,
    float* __restrict__ cost)
{
    __shared__ float s2t[16][Cq + 1];   // stride 92 -> 2-way bank alias (free)
    __shared__ float s1t[16][Cq + 1];
    __shared__ float b2x[16], b2y[16], b1x[16], b1y[16];
    const int b  = blockIdx.z;
    const int i0 = blockIdx.y * 16;
    const int j0 = blockIdx.x * 16;
    const int tid = threadIdx.x;

    for (int t = tid; t < 16 * Cq; t += 256) {
        const int r = t / Cq, c = t - r * Cq;
        const int i = min(i0 + r, Mq - 1);
        const int j = min(j0 + r, Nq - 1);
        s2t[r][c] = sigmoidf_(p2_logits[((size_t)b * Mq + i) * Cq + c]);
        s1t[r][c] = sigmoidf_(p1_logits[((size_t)b * Nq + j) * Cq + c]);
    }
    if (tid < 16) {
        const int i = min(i0 + tid, Mq - 1);
        const int j = min(j0 + tid, Nq - 1);
        b2x[tid] = p2_boxes[((size_t)b * Mq + i) * 4 + 0];
        b2y[tid] = p2_boxes[((size_t)b * Mq + i) * 4 + 1];
        b1x[tid] = p1_boxes[((size_t)b * Nq + j) * 4 + 0];
        b1y[tid] = p1_boxes[((size_t)b * Nq + j) * 4 + 1];
    }
    __syncthreads();

    const int ty = tid >> 4, tx = tid & 15;
    const int i = i0 + ty, j = j0 + tx;
    if (i < Mq && j < Nq) {
        float mx = 0.0f;
        #pragma unroll 7
        for (int c = 0; c < Cq; ++c)
            mx = fmaxf(mx, fabsf(s2t[ty][c] - s1t[tx][c]));
        const float dx = b2x[ty] - b1x[tx];
        const float dy = b2y[ty] - b1y[tx];
        const float cd = sqrtf(dx * dx + dy * dy);
        cost[((size_t)b * Mq + i) * Nq + j] = 0.5f * cd + 0.5f * mx;
    }
}

// ---------------------------------------------------------------------------
// Phase 1.5: column reduction. v0[b][j] = min_i cost[b][i][j], amin = argmin.
// ---------------------------------------------------------------------------
__global__ __launch_bounds__(256) void colred_kernel(
    const float* __restrict__ cost, float* __restrict__ v0, int* __restrict__ amin)
{
    const int j = blockIdx.x * 256 + threadIdx.x;
    const int b = blockIdx.y;
    if (j >= Nq) return;
    const float* __restrict__ cb = cost + (size_t)b * Mq * Nq;
    float best = INFINITY;
    int bi = 0;
    #pragma unroll 4
    for (int i = 0; i < Mq; ++i) {
        const float c = cb[(size_t)i * Nq + j];
        if (c < best) { best = c; bi = i; }
    }
    v0[b * Nq + j] = best;
    amin[b * Nq + j] = bi;
}

// ---------------------------------------------------------------------------
// DPP wave64 reductions (VALU-only; no LDS pipe). row_shr 1/2/4/8 +
// row_bcast15/31 leaves the full-wave min in lane 63; readlane broadcasts.
// ---------------------------------------------------------------------------
template<int CTRL>
__device__ __forceinline__ float dppmin_f32_(float x) {
    const int moved = __builtin_amdgcn_update_dpp(
        0x7F800000 /* +inf for invalid src */, __float_as_int(x), CTRL, 0xF, 0xF, false);
    return fminf(x, __int_as_float(moved));
}
__device__ __forceinline__ float wave_min_f32_(float x) {
    x = dppmin_f32_<0x111>(x);  // row_shr:1
    x = dppmin_f32_<0x112>(x);  // row_shr:2
    x = dppmin_f32_<0x114>(x);  // row_shr:4
    x = dppmin_f32_<0x118>(x);  // row_shr:8
    x = dppmin_f32_<0x142>(x);  // row_bcast:15
    x = dppmin_f32_<0x143>(x);  // row_bcast:31
    return __int_as_float(__builtin_amdgcn_readlane(__float_as_int(x), 63));
}
template<int CTRL>
__device__ __forceinline__ unsigned dppmin_u32_(unsigned x) {
    const unsigned moved = (unsigned)__builtin_amdgcn_update_dpp(
        (int)0xFFFFFFFFu, (int)x, CTRL, 0xF, 0xF, false);
    return x < moved ? x : moved;
}
__device__ __forceinline__ unsigned wave_min_u32_(unsigned x) {
    x = dppmin_u32_<0x111>(x);
    x = dppmin_u32_<0x112>(x);
    x = dppmin_u32_<0x114>(x);
    x = dppmin_u32_<0x118>(x);
    x = dppmin_u32_<0x142>(x);
    x = dppmin_u32_<0x143>(x);
    return (unsigned)__builtin_amdgcn_readlane((int)x, 63);
}

// ---------------------------------------------------------------------------
// Phase 2: exact successive-shortest-path LAP (identical pop sequence to the
// reference's LAPJV port given the column-reduction+greedy start; unique
// optimum on continuous random data => identical mapping). One block = one
// batch, ONE wave. Lane L owns columns {L, L+64, ...}; v/shortest/path/
// remaining in registers. Per pop: coalesced L2 row load -> register relax ->
// speculative ds_read_b64 of pair_lds[local argmin] (latency hidden under the
// DPP trees) -> f32-min DPP tree -> u32-argmin DPP tree (lowest-j tie-break)
// -> readlane of the winner lane's speculative pair. Zero barriers per pop.
// ---------------------------------------------------------------------------
__global__ __launch_bounds__(64) void lsa_kernel(
    const float* __restrict__ cost, const float* __restrict__ v0,
    const int* __restrict__ amin, int* __restrict__ mapping)
{
    constexpr int n = Nq;  // 500
    __shared__ int2  pair_lds[512];      // {row4col[j], f32bits(u[row4col[j]])}
    __shared__ float u_lds[512];
    __shared__ float shortest_lds[512];
    __shared__ int   path_lds[512];
    __shared__ int   row4col_lds[512];
    __shared__ int   col4row_lds[512];

    const int lane = threadIdx.x;
    const int b = blockIdx.x;
    const float* __restrict__ cb = cost + (size_t)b * n * n;

    const unsigned init_mask = (lane < (n & 63)) ? 0xFFu : 0x7Fu;  // k=7 valid iff lane<52

    float v_r[8], short_r[8];
    int path_r[8];

    // --- init: duals from column reduction, greedy matching on tight edges ---
    #pragma unroll
    for (int k = 0; k < 8; ++k) {
        const int j = lane + (k << 6);
        v_r[k] = (j < n) ? v0[b * n + j] : 0.0f;
        short_r[k] = INFINITY;
        path_r[k] = -1;
        if (j < n) path_lds[j] = amin[b * n + j];   // stash argmins for lane0
    }
    for (int t = lane; t < 512; t += 64) {
        u_lds[t] = 0.0f; row4col_lds[t] = -1; col4row_lds[t] = -1;
    }
    __syncthreads();
    if (lane == 0) {
        for (int j = 0; j < n; ++j) {
            const int i0 = path_lds[j];
            if (col4row_lds[i0] < 0) { col4row_lds[i0] = j; row4col_lds[j] = i0; }
        }
    }
    __syncthreads();
    #pragma unroll
    for (int k = 0; k < 8; ++k) {
        const int j = lane + (k << 6);
        if (j < n) {
            const int rr = row4col_lds[j];
            pair_lds[j] = make_int2(rr, rr >= 0 ? __float_as_int(u_lds[rr]) : 0);
            path_lds[j] = -1;
        }
    }
    unsigned rem = init_mask;
    unsigned sr_mask = 0;
    __syncthreads();

    // --- successive shortest paths over unassigned rows ---
    for (int cur_row = 0; cur_row < n; ++cur_row) {
        if (col4row_lds[cur_row] >= 0) continue;   // wave-uniform

        int sink = -1;
        int i = cur_row;
        float min_val = 0.0f;
        float a = -u_lds[cur_row];                  // a = min_val - u[i]
        const float* __restrict__ crow = cb + (size_t)i * n;

        for (;;) {
            if (((i ^ lane) & 63) == 0) sr_mask |= 1u << (i >> 6);

            float cv[8];
            #pragma unroll
            for (int k = 0; k < 8; ++k) {
                const int j = lane + (k << 6);
                cv[k] = crow[j < n ? j : 0];
            }

            float lmin = INFINITY;
            unsigned lidx = 0xFFFFFFFFu;
            #pragma unroll
            for (int k = 0; k < 8; ++k) {
                if (rem & (1u << k)) {
                    const int j = lane + (k << 6);
                    const float r = fmaxf(a + cv[k] - v_r[k], 0.0f);
                    if (r < short_r[k]) { short_r[k] = r; path_r[k] = i; }
                    // k ascending => '<' keeps this lane's lowest tying j
                    if (short_r[k] < lmin) { lmin = short_r[k]; lidx = (unsigned)j; }
                }
            }

            // speculative (row4col,u) read for this lane's candidate; the
            // winner lane's value is exactly pair_lds[jst]. Hidden under DPP.
            const int safei = (lidx < (unsigned)n) ? (int)lidx : 0;
            const int2 spec = pair_lds[safei];

            const float gmin = wave_min_f32_(lmin);
            const unsigned cand = (lmin == gmin) ? lidx : 0xFFFFFFFFu;
            const unsigned jst = wave_min_u32_(cand);

            min_val = gmin;
            if (((jst ^ (unsigned)lane) & 63u) == 0u) rem &= ~(1u << (jst >> 6));

            const int owner = (int)(jst & 63u);
            const int prx = __builtin_amdgcn_readlane(spec.x, owner);
            const int pry = __builtin_amdgcn_readlane(spec.y, owner);
            if (prx < 0) { sink = (int)jst; break; }
            i = prx;
            a = gmin - __int_as_float(pry);
            crow = cb + (size_t)i * n;
        }

        // --- end of row: publish shortest/path ---
        #pragma unroll
        for (int k = 0; k < 8; ++k) {
            const int j = lane + (k << 6);
            if (j < n) { shortest_lds[j] = short_r[k]; path_lds[j] = path_r[k]; }
        }
        __syncthreads();

        // dual updates (col4row read BEFORE augmentation, per reference)
        #pragma unroll
        for (int k = 0; k < 8; ++k) {
            const int t = lane + (k << 6);
            if (t < n && (sr_mask & (1u << k))) {
                if (t == cur_row) u_lds[t] += min_val;
                else              u_lds[t] += min_val - shortest_lds[col4row_lds[t]];
            }
        }
        const unsigned scanned = init_mask & ~rem;
        #pragma unroll
        for (int k = 0; k < 8; ++k)
            if (scanned & (1u << k)) v_r[k] -= min_val - short_r[k];
        __syncthreads();

        if (lane == 0) {   // augment alternating path
            int j = sink;
            for (;;) {
                const int ii = path_lds[j];
                row4col_lds[j] = ii;
                const int tmp = col4row_lds[ii];
                col4row_lds[ii] = j;
                j = tmp;
                if (ii == cur_row) break;
            }
        }
        __syncthreads();

        // rebuild (row4col, u) pairs; reset per-row register state
        #pragma unroll
        for (int k = 0; k < 8; ++k) {
            const int j = lane + (k << 6);
            if (j < n) {
                const int rr = row4col_lds[j];
                pair_lds[j] = make_int2(rr, rr >= 0 ? __float_as_int(u_lds[rr]) : 0);
            }
            short_r[k] = INFINITY;
            path_r[k] = -1;
        }
        rem = init_mask;
        sr_mask = 0;
        __syncthreads();
    }

    for (int t = lane; t < n; t += 64)
        mapping[b * n + t] = col4row_lds[t];
}

// ---------------------------------------------------------------------------
// Phase 3: extrapolation (square problem => every row assigned).
// ---------------------------------------------------------------------------
__global__ __launch_bounds__(256) void extrap_boxes_kernel(
    const float* __restrict__ p1_boxes, const float* __restrict__ p2_boxes,
    const float* __restrict__ toffs, const int* __restrict__ mapping,
    float* __restrict__ out_boxes)
{
    const int idx = blockIdx.x * blockDim.x + threadIdx.x;  // b*Mq + i
    if (idx >= Bq * Mq) return;
    const int b = idx / Mq;
    const float t0 = toffs[b * 3 + 0], t1 = toffs[b * 3 + 1], t2 = toffs[b * 3 + 2];
    const float factor = (t2 - t1) / (t1 - t0);
    const int m = mapping[idx];
    const float4 p2 = ((const float4*)p2_boxes)[idx];
    const float4 p1 = ((const float4*)p1_boxes)[b * Nq + m];
    float4 o;
    o.x = p2.x + (p2.x - p1.x) * factor;
    o.y = p2.y + (p2.y - p1.y) * factor;
    o.z = fmaxf(p2.z + (p2.z - p1.z) * factor, 0.0f);
    o.w = fmaxf(p2.w + (p2.w - p1.w) * factor, 0.0f);
    ((float4*)out_boxes)[idx] = o;
}

__global__ __launch_bounds__(256) void extrap_logits_kernel(
    const float* __restrict__ p1_logits, const float* __restrict__ p2_logits,
    const int* __restrict__ mapping, float* __restrict__ out_logits)
{
    const int idx = blockIdx.x * blockDim.x + threadIdx.x;  // (b*Mq + i)*Cq + c
    if (idx >= Bq * Mq * Cq) return;
    const int c = idx % Cq;
    const int bi = idx / Cq;
    const int b = bi / Mq;
    const int m = mapping[bi];
    out_logits[idx] = 0.5f * (p2_logits[idx] + p1_logits[((size_t)b * Nq + m) * Cq + c]);
}

// ---------------------------------------------------------------------------
extern "C" void kernel_launch(void* const* d_in, const int* in_sizes, int n_in,
                              void* d_out, int out_size, void* d_ws, size_t ws_size,
                              hipStream_t stream) {
    const float* p1_boxes  = (const float*)d_in[0];  // (B,N,4)
    const float* p1_logits = (const float*)d_in[1];  // (B,N,C)
    const float* p2_boxes  = (const float*)d_in[2];  // (B,M,4)
    const float* p2_logits = (const float*)d_in[3];  // (B,M,C)
    const float* toffs     = (const float*)d_in[4];  // (B,3)
    float* out = (float*)d_out;                      // boxes3 ++ logits3

    char* ws = (char*)d_ws;
    float* cost    = (float*)ws;                                   // 4 MB
    int*   mapping = (int*)  (ws + 4000000);                       // 8 KB
    float* v0      = (float*)(ws + 4008000);                       // 8 KB
    int*   amin    = (int*)  (ws + 4016000);                       // 8 KB

    dim3 cgrid((Nq + 15) / 16, (Mq + 15) / 16, Bq);
    cost_kernel<<<cgrid, 256, 0, stream>>>(p1_boxes, p1_logits, p2_boxes, p2_logits, cost);

    colred_kernel<<<dim3(2, Bq), 256, 0, stream>>>(cost, v0, amin);

    lsa_kernel<<<Bq, 64, 0, stream>>>(cost, v0, amin, mapping);

    extrap_boxes_kernel<<<(Bq * Mq + 255) / 256, 256, 0, stream>>>(
        p1_boxes, p2_boxes, toffs, mapping, out);
    extrap_logits_kernel<<<(Bq * Mq * Cq + 255) / 256, 256, 0, stream>>>(
        p1_logits, p2_logits, mapping, out + Bq * Mq * 4);
}